// Round 3
// baseline (314.300 us; speedup 1.0000x reference)
//
#include <hip/hip_runtime.h>
#include <hip/hip_bf16.h>
#include <cstdint>
#include <cstddef>

// Fused multi-head "Head" op on MI355X (gfx950), bf16-MFMA path.
// B=8, S=4096, D=512, T=8, c=S/T=512. All matmuls are 512^3 per (b,t), 64 (b,t) pairs.
//
// Pipeline (all on `stream`):
//   1. pe_cast:   x_pe = bf16(x + sinusoidal_pe)               [ws]
//   2. cast_w:    Wk,Wq,Wv -> bf16                             [ws]
//   3. gemm k  = x_pe . Wk^T + bk   (bias over cols) -> bf16   [ws]
//   4. gemm q  = x_pe . Wq^T + bq                    -> bf16   [ws]
//   5. gemm vT = Wv . x_pe^T + bv   (bias over rows) -> bf16   [ws]  (v stored transposed!)
//   6. gemm scores = (k . q^T) / 512                 -> fp32   [d_out as scratch]
//   7. softmax rows -> attn bf16                               [ws, aliases dead x_pe]
//   8. gemm out = attn . v  (B-op = vT, NT form)     -> fp32   [d_out]
//
// ws requirement: 146,800,640 bytes (~140 MiB).

typedef __bf16 bf16_t;
typedef __bf16 bf16x4 __attribute__((ext_vector_type(4)));
typedef __bf16 bf16x8 __attribute__((ext_vector_type(8)));
typedef float  f32x4  __attribute__((ext_vector_type(4)));

#define GAS __attribute__((address_space(1)))
#define LAS __attribute__((address_space(3)))

// ---------------------------------------------------------------------------
// 1. PE add + cast to bf16.  total = B*S*D elements, processed as float4.
// pe(s,d): even d -> sin(s*div), odd d -> cos(s*div), div = exp(-ln(1e4)/512 * (d&~1))
// ---------------------------------------------------------------------------
__global__ __launch_bounds__(256) void pe_cast_kernel(
    const float* __restrict__ x, bf16_t* __restrict__ xpe, int n4)
{
    const float cexp = -0.017988946039015984f; // -ln(10000)/512
    for (int i = blockIdx.x * 256 + threadIdx.x; i < n4; i += gridDim.x * 256) {
        int e0 = i << 2;
        int d  = e0 & 511;          // D = 512
        int s  = (e0 >> 9) & 4095;  // S = 4096
        float4 xv = ((const float4*)x)[i];
        float fs = (float)s;
        float a0 = fs * __expf(cexp * (float)d);
        float a1 = fs * __expf(cexp * (float)(d + 2));
        float s0, c0, s1, c1;
        sincosf(a0, &s0, &c0);   // precise version: args up to ~4096 need real reduction
        sincosf(a1, &s1, &c1);
        bf16x4 o;
        o[0] = (bf16_t)(xv.x + s0);
        o[1] = (bf16_t)(xv.y + c0);
        o[2] = (bf16_t)(xv.z + s1);
        o[3] = (bf16_t)(xv.w + c1);
        ((bf16x4*)xpe)[i] = o;
    }
}

// ---------------------------------------------------------------------------
// 2. fp32 -> bf16 cast for the three weight tensors (grid.y selects tensor)
// ---------------------------------------------------------------------------
__global__ __launch_bounds__(256) void cast_w(
    const float* __restrict__ w0, const float* __restrict__ w1, const float* __restrict__ w2,
    bf16_t* __restrict__ o0, bf16_t* __restrict__ o1, bf16_t* __restrict__ o2, int n4)
{
    const float* s = blockIdx.y == 0 ? w0 : (blockIdx.y == 1 ? w1 : w2);
    bf16_t*      o = blockIdx.y == 0 ? o0 : (blockIdx.y == 1 ? o1 : o2);
    for (int i = blockIdx.x * 256 + threadIdx.x; i < n4; i += gridDim.x * 256) {
        float4 v = ((const float4*)s)[i];
        bf16x4 r;
        r[0] = (bf16_t)v.x; r[1] = (bf16_t)v.y; r[2] = (bf16_t)v.z; r[3] = (bf16_t)v.w;
        ((bf16x4*)o)[i] = r;
    }
}

// ---------------------------------------------------------------------------
// NT GEMM template: C[m][n] = scale * sum_k A[m][k]*B[n][k] (+bias)
// M=N=K=512, grid=(16 tiles, 64 bt). 128x128 tile, BK=64, 4 waves (2x2 of 64x64),
// mfma_f32_16x16x32_bf16. global_load_lds(16B) staging with XOR-swizzled GLOBAL
// source + XOR on the LDS read (rule #21: linear dest, both-sides swizzle)
// -> conflict-free ds_read_b128.
//   LDS row r, 16B-slot s holds global k-chunk (s ^ (r&7));
//   read of k-chunk kc at row r fetches slot kc ^ (r&7); row&7 == l&7 for frags.
// BIAS_MODE: 0 none, 1 bias[col] (+t*512), 2 bias[row] (+t*512)
// OUT_BF16:  1 -> bf16 C, 0 -> fp32 C
// aByT/bByT: operand offset = (byT ? bt&7 : bt) * stride  (weights indexed by t only)
// ---------------------------------------------------------------------------
template<int BIAS_MODE, int OUT_BF16>
__global__ __launch_bounds__(256, 2) void gemm_nt(
    const bf16_t* __restrict__ A, const bf16_t* __restrict__ Bm,
    void* __restrict__ C, const float* __restrict__ bias,
    long aStr, long bStr, long cStr, int aByT, int bByT, float scale)
{
    constexpr int LD = 512;
    int bt = blockIdx.y;
    int t  = bt & 7;
    const bf16_t* Ab = A  + (size_t)(aByT ? t : bt) * aStr;
    const bf16_t* Bb = Bm + (size_t)(bByT ? t : bt) * bStr;
    int ti = (blockIdx.x >> 2) << 7;   // row-tile origin
    int tn = (blockIdx.x & 3) << 7;    // col-tile origin

    __shared__ bf16_t lds[16384];      // A tile: bytes [0,16384), B tile: [16384,32768)
    char* ldsA = (char*)&lds[0];
    char* ldsB = (char*)&lds[8192];

    const int tid  = threadIdx.x;
    const int l    = tid & 63;
    const int w    = tid >> 6;
    const int lrow = l >> 3;               // staging: row within 8-row chunk
    const int hd   = (l & 7) ^ lrow;       // staging: pre-swizzled k-chunk (16B units)
    const int wrow = w >> 1, wcol = w & 1; // wave grid 2x2
    const int rA   = l & 15;               // frag row/col within 16
    const int hb   = l >> 4;               // frag k-subchunk 0..3
    const int x7   = l & 7;                // read-side XOR key (== row&7 since frags start at x16)

    f32x4 acc[4][4] = {};

    for (int k0 = 0; k0 < 512; k0 += 64) {
        __syncthreads();  // previous compute done before overwriting LDS
        #pragma unroll
        for (int p = 0; p < 4; ++p) {
            int c    = w * 4 + p;          // 1KB chunk id, 16 per tile
            int grow = c * 8 + lrow;       // tile row 0..127
            const bf16_t* srcA = Ab + (size_t)(ti + grow) * LD + k0 + hd * 8;
            const bf16_t* srcB = Bb + (size_t)(tn + grow) * LD + k0 + hd * 8;
            __builtin_amdgcn_global_load_lds((GAS void*)srcA, (LAS void*)(ldsA + c * 1024 + l * 16), 16, 0, 0);
            __builtin_amdgcn_global_load_lds((GAS void*)srcB, (LAS void*)(ldsB + c * 1024 + l * 16), 16, 0, 0);
        }
        __syncthreads();  // compiler drains vmcnt before barrier -> tiles ready
        #pragma unroll
        for (int kk = 0; kk < 2; ++kk) {
            bf16x8 a[4], b[4];
            #pragma unroll
            for (int m = 0; m < 4; ++m) {
                int off = (wrow * 64 + m * 16 + rA) * 128 + ((((kk << 2) | hb)) ^ x7) * 16;
                a[m] = *(const bf16x8*)(ldsA + off);
            }
            #pragma unroll
            for (int n = 0; n < 4; ++n) {
                int off = (wcol * 64 + n * 16 + rA) * 128 + ((((kk << 2) | hb)) ^ x7) * 16;
                b[n] = *(const bf16x8*)(ldsB + off);
            }
            #pragma unroll
            for (int m = 0; m < 4; ++m)
                #pragma unroll
                for (int n = 0; n < 4; ++n)
                    acc[m][n] = __builtin_amdgcn_mfma_f32_16x16x32_bf16(a[m], b[n], acc[m][n], 0, 0, 0);
        }
    }

    // Epilogue. D frag: col = l&15, row = (l>>4)*4 + reg  (m89/m91-verified)
    const float* biasT = bias ? bias + t * 512 : bias;
    int r0 = ti + wrow * 64;
    int c0 = tn + wcol * 64;
    #pragma unroll
    for (int m = 0; m < 4; ++m) {
        #pragma unroll
        for (int n = 0; n < 4; ++n) {
            int col = c0 + n * 16 + rA;
            float bc = (BIAS_MODE == 1) ? biasT[col] : 0.0f;
            f32x4 v = acc[m][n];
            #pragma unroll
            for (int r = 0; r < 4; ++r) {
                int row = r0 + m * 16 + hb * 4 + r;
                float val = v[r] * scale + ((BIAS_MODE == 2) ? biasT[row] : bc);
                size_t off = (size_t)bt * cStr + (size_t)row * LD + col;
                if (OUT_BF16) ((bf16_t*)C)[off] = (bf16_t)val;
                else          ((float*)C)[off]  = val;
            }
        }
    }
}

// ---------------------------------------------------------------------------
// 7. Row softmax: 32768 rows of 512 fp32 -> bf16. One wave per row.
// ---------------------------------------------------------------------------
__global__ __launch_bounds__(256) void softmax_rows(
    const float* __restrict__ S, bf16_t* __restrict__ P)
{
    int row = blockIdx.x * 4 + (threadIdx.x >> 6);
    int l   = threadIdx.x & 63;
    const float4* rp = (const float4*)(S + (size_t)row * 512);
    float4 v0 = rp[l];        // cols l*4 .. l*4+3
    float4 v1 = rp[64 + l];   // cols 256+l*4 ..
    float m = fmaxf(fmaxf(fmaxf(v0.x, v0.y), fmaxf(v0.z, v0.w)),
                    fmaxf(fmaxf(v1.x, v1.y), fmaxf(v1.z, v1.w)));
    #pragma unroll
    for (int off = 32; off; off >>= 1) m = fmaxf(m, __shfl_xor(m, off, 64));
    float e0 = __expf(v0.x - m), e1 = __expf(v0.y - m), e2 = __expf(v0.z - m), e3 = __expf(v0.w - m);
    float e4 = __expf(v1.x - m), e5 = __expf(v1.y - m), e6 = __expf(v1.z - m), e7 = __expf(v1.w - m);
    float sum = ((e0 + e1) + (e2 + e3)) + ((e4 + e5) + (e6 + e7));
    #pragma unroll
    for (int off = 32; off; off >>= 1) sum += __shfl_xor(sum, off, 64);
    float inv = 1.0f / sum;
    bf16x4 r0, r1;
    r0[0] = (bf16_t)(e0 * inv); r0[1] = (bf16_t)(e1 * inv);
    r0[2] = (bf16_t)(e2 * inv); r0[3] = (bf16_t)(e3 * inv);
    r1[0] = (bf16_t)(e4 * inv); r1[1] = (bf16_t)(e5 * inv);
    r1[2] = (bf16_t)(e6 * inv); r1[3] = (bf16_t)(e7 * inv);
    bf16x4* wp = (bf16x4*)(P + (size_t)row * 512);
    wp[l] = r0; wp[64 + l] = r1;
}

// ---------------------------------------------------------------------------
extern "C" void kernel_launch(void* const* d_in, const int* in_sizes, int n_in,
                              void* d_out, int out_size, void* d_ws, size_t ws_size,
                              hipStream_t stream)
{
    const float* x  = (const float*)d_in[0];
    const float* Wk = (const float*)d_in[1];
    const float* bk = (const float*)d_in[2];
    const float* Wq = (const float*)d_in[3];
    const float* bq = (const float*)d_in[4];
    const float* Wv = (const float*)d_in[5];
    const float* bv = (const float*)d_in[6];
    float* out = (float*)d_out;
    char*  ws  = (char*)d_ws;

    // ws layout (bytes); total 146,800,640 (~140 MiB)
    bf16_t* k    = (bf16_t*)(ws + 0);          // 33.55 MB
    bf16_t* q    = (bf16_t*)(ws + 33554432);   // 33.55 MB
    bf16_t* vt   = (bf16_t*)(ws + 67108864);   // 33.55 MB  (v transposed: [bt][e][i])
    bf16_t* xpe  = (bf16_t*)(ws + 100663296);  // 33.55 MB  (dead after vt gemm)
    bf16_t* attn = xpe;                        // alias over dead xpe
    bf16_t* wkb  = (bf16_t*)(ws + 134217728);  // 4.19 MB
    bf16_t* wqb  = (bf16_t*)(ws + 138412032);  // 4.19 MB
    bf16_t* wvb  = (bf16_t*)(ws + 142606336);  // 4.19 MB
    float* scores = out;                       // d_out (64 MB fp32) doubles as scores scratch

    const long S2 = 262144;  // 512*512, the universal per-(b,t)/per-t stride

    pe_cast_kernel<<<2048, 256, 0, stream>>>(x, xpe, (8 * 4096 * 512) / 4);
    cast_w<<<dim3(512, 3), 256, 0, stream>>>(Wk, Wq, Wv, wkb, wqb, wvb, (8 * 512 * 512) / 4);

    dim3 gg(16, 64);
    // k = xpe . Wk^T + bk (col bias)
    gemm_nt<1, 1><<<gg, 256, 0, stream>>>(xpe, wkb, k, bk, S2, S2, S2, 0, 1, 1.0f);
    // q = xpe . Wq^T + bq
    gemm_nt<1, 1><<<gg, 256, 0, stream>>>(xpe, wqb, q, bq, S2, S2, S2, 0, 1, 1.0f);
    // v^T = Wv . xpe^T + bv (row bias)  -> vt[e][i]
    gemm_nt<2, 1><<<gg, 256, 0, stream>>>(wvb, xpe, vt, bv, S2, S2, S2, 1, 0, 1.0f);
    // scores = (k . q^T) / 512 -> d_out (fp32 scratch)
    gemm_nt<0, 0><<<gg, 256, 0, stream>>>(k, q, scores, nullptr, S2, S2, S2, 0, 0, 1.0f / 512.0f);
    // attn = softmax(scores) -> bf16 (over dead xpe)
    softmax_rows<<<8192, 256, 0, stream>>>(scores, attn);
    // out = attn . v  (B-op = vt, NT) -> d_out fp32
    gemm_nt<0, 0><<<gg, 256, 0, stream>>>(attn, vt, out, nullptr, S2, S2, S2, 0, 0, 1.0f);
}

// Round 4
// 274.094 us; speedup vs baseline: 1.1467x; 1.1467x over previous
//
#include <hip/hip_runtime.h>
#include <hip/hip_bf16.h>
#include <cstdint>
#include <cstddef>

// Fused multi-head "Head" op on MI355X (gfx950), bf16-MFMA path.
// B=8, S=4096, D=512, T=8, c=512. 64 (b,t) heads, each a 512^3 GEMM chain.
//
// Pipeline:
//   1. pe_cast:  x_pe = bf16(x + PE)      (trig amortized over batch)   [ws]
//   2. cast_w:   Wk,Wq,Wv -> bf16                                       [ws]
//   3. gemm k, q (col bias), vT (row bias; v stored transposed)         [ws]
//   4. scores_softmax: attn = softmax(k.q^T/512) fused, bf16            [ws]
//   5. gemm out = attn . v (NT vs vT) -> fp32                           [d_out]
// All GEMM grids XCD-swizzled (T1); all GEMM staging 2-phase double-buffered.
// ws requirement: 146,800,640 bytes (~140 MiB).

typedef __bf16 bf16_t;
typedef __bf16 bf16x4 __attribute__((ext_vector_type(4)));
typedef __bf16 bf16x8 __attribute__((ext_vector_type(8)));
typedef float  f32x4  __attribute__((ext_vector_type(4)));

#define GAS __attribute__((address_space(1)))
#define LAS __attribute__((address_space(3)))

// ---------------------------------------------------------------------------
// 1. PE add + cast. One thread owns (s, d4) and loops over the 8 batches,
// so sincos count is amortized 8x. Lanes are d4-consecutive -> coalesced.
// ---------------------------------------------------------------------------
__global__ __launch_bounds__(256) void pe_cast_kernel(
    const float* __restrict__ x, bf16_t* __restrict__ xpe)
{
    const float cexp = -0.017988946039015984f; // -ln(10000)/512
    int i = blockIdx.x * 256 + threadIdx.x;    // [0, 4096*128)
    int d4 = i & 127;
    int s  = i >> 7;
    int d  = d4 * 4;
    float fs = (float)s;
    float a0 = fs * __expf(cexp * (float)d);
    float a1 = fs * __expf(cexp * (float)(d + 2));
    float s0, c0, s1, c1;
    sincosf(a0, &s0, &c0);
    sincosf(a1, &s1, &c1);
    size_t base = (size_t)s * 512 + d;
    #pragma unroll
    for (int b = 0; b < 8; ++b) {
        float4 xv = *(const float4*)(x + (size_t)b * 2097152 + base);
        bf16x4 o;
        o[0] = (bf16_t)(xv.x + s0);
        o[1] = (bf16_t)(xv.y + c0);
        o[2] = (bf16_t)(xv.z + s1);
        o[3] = (bf16_t)(xv.w + c1);
        *(bf16x4*)(xpe + (size_t)b * 2097152 + base) = o;
    }
}

// ---------------------------------------------------------------------------
// 2. fp32 -> bf16 cast for the three weight tensors (grid.y selects tensor)
// ---------------------------------------------------------------------------
__global__ __launch_bounds__(256) void cast_w(
    const float* __restrict__ w0, const float* __restrict__ w1, const float* __restrict__ w2,
    bf16_t* __restrict__ o0, bf16_t* __restrict__ o1, bf16_t* __restrict__ o2, int n4)
{
    const float* s = blockIdx.y == 0 ? w0 : (blockIdx.y == 1 ? w1 : w2);
    bf16_t*      o = blockIdx.y == 0 ? o0 : (blockIdx.y == 1 ? o1 : o2);
    for (int i = blockIdx.x * 256 + threadIdx.x; i < n4; i += gridDim.x * 256) {
        float4 v = ((const float4*)s)[i];
        bf16x4 r;
        r[0] = (bf16_t)v.x; r[1] = (bf16_t)v.y; r[2] = (bf16_t)v.z; r[3] = (bf16_t)v.w;
        ((bf16x4*)o)[i] = r;
    }
}

// ---------------------------------------------------------------------------
// NT GEMM: C[m][n] = scale*sum_k A[m][k]*B[n][k] (+bias). M=N=K=512.
// 128x128 tile, BK=64, 4 waves (2x2 of 64x64), mfma_f32_16x16x32_bf16.
// 2-phase double-buffered global_load_lds(16B) staging; rule-#21 both-sides
// XOR swizzle (linear LDS dest, pre-swizzled global source, XOR on read).
// Grid XCD-swizzled: 1024 blocks -> w=(L&7)*128 + L/8 (bijective, 1024%8==0).
// ---------------------------------------------------------------------------
template<int BIAS_MODE, int OUT_BF16>   // BIAS: 0 none, 1 col, 2 row
__global__ __launch_bounds__(256, 2) void gemm_nt(
    const bf16_t* __restrict__ A, const bf16_t* __restrict__ Bm,
    void* __restrict__ C, const float* __restrict__ bias,
    long aStr, long bStr, long cStr, int aByT, int bByT, float scale)
{
    constexpr int LD = 512;
    int L  = blockIdx.y * 16 + blockIdx.x;      // 0..1023
    int wk = (L & 7) * 128 + (L >> 3);          // XCD swizzle (T1, bijective)
    int bt = wk >> 4;
    int tile = wk & 15;
    int t  = bt & 7;
    const bf16_t* Ab = A  + (size_t)(aByT ? t : bt) * aStr;
    const bf16_t* Bb = Bm + (size_t)(bByT ? t : bt) * bStr;
    int ti = (tile >> 2) << 7;   // row-tile origin
    int tn = (tile & 3) << 7;    // col-tile origin

    __shared__ __align__(1024) char lds[65536];  // dbuf: [b][A 16K | B 16K]

    const int tid  = threadIdx.x;
    const int l    = tid & 63;
    const int w    = tid >> 6;
    const int lrow = l >> 3;               // staging row within 8-row chunk
    const int hd   = (l & 7) ^ lrow;       // pre-swizzled global k-chunk
    const int wrow = w >> 1, wcol = w & 1;
    const int rA   = l & 15;
    const int hb   = l >> 4;
    const int x7   = l & 7;                // read-side XOR (== row&7 for frags)

    f32x4 acc[4][4] = {};

    auto stage = [&](int buf, int k0) {
        char* ldsA = lds + buf * 32768;
        char* ldsB = ldsA + 16384;
        #pragma unroll
        for (int p = 0; p < 4; ++p) {
            int c    = w * 4 + p;
            int grow = c * 8 + lrow;
            const bf16_t* srcA = Ab + (size_t)(ti + grow) * LD + k0 + hd * 8;
            const bf16_t* srcB = Bb + (size_t)(tn + grow) * LD + k0 + hd * 8;
            __builtin_amdgcn_global_load_lds((GAS void*)srcA, (LAS void*)(ldsA + c * 1024 + l * 16), 16, 0, 0);
            __builtin_amdgcn_global_load_lds((GAS void*)srcB, (LAS void*)(ldsB + c * 1024 + l * 16), 16, 0, 0);
        }
    };

    stage(0, 0);
    __syncthreads();                     // vmcnt(0) drained by compiler -> buf0 ready
    for (int it = 0; it < 8; ++it) {
        if (it < 7) stage((it + 1) & 1, (it + 1) * 64);   // prefetch overlaps compute
        const char* ldsA = lds + (it & 1) * 32768;
        const char* ldsB = ldsA + 16384;
        #pragma unroll
        for (int kk = 0; kk < 2; ++kk) {
            bf16x8 a[4], b[4];
            #pragma unroll
            for (int m = 0; m < 4; ++m) {
                int off = (wrow * 64 + m * 16 + rA) * 128 + ((((kk << 2) | hb)) ^ x7) * 16;
                a[m] = *(const bf16x8*)(ldsA + off);
            }
            #pragma unroll
            for (int n = 0; n < 4; ++n) {
                int off = (wcol * 64 + n * 16 + rA) * 128 + ((((kk << 2) | hb)) ^ x7) * 16;
                b[n] = *(const bf16x8*)(ldsB + off);
            }
            #pragma unroll
            for (int m = 0; m < 4; ++m)
                #pragma unroll
                for (int n = 0; n < 4; ++n)
                    acc[m][n] = __builtin_amdgcn_mfma_f32_16x16x32_bf16(a[m], b[n], acc[m][n], 0, 0, 0);
        }
        __syncthreads();                 // next buf staged + this buf consumed
    }

    // Epilogue. D frag: col = l&15, row = (l>>4)*4 + reg  (m89/m91-verified)
    const float* biasT = bias ? bias + t * 512 : bias;
    int r0 = ti + wrow * 64;
    int c0 = tn + wcol * 64;
    #pragma unroll
    for (int m = 0; m < 4; ++m) {
        #pragma unroll
        for (int n = 0; n < 4; ++n) {
            int col = c0 + n * 16 + rA;
            float bc = (BIAS_MODE == 1) ? biasT[col] : 0.0f;
            f32x4 v = acc[m][n];
            #pragma unroll
            for (int r = 0; r < 4; ++r) {
                int row = r0 + m * 16 + hb * 4 + r;
                float val = v[r] * scale + ((BIAS_MODE == 2) ? biasT[row] : bc);
                size_t off = (size_t)bt * cStr + (size_t)row * LD + col;
                if (OUT_BF16) ((bf16_t*)C)[off] = (bf16_t)val;
                else          ((float*)C)[off]  = val;
            }
        }
    }
}

// ---------------------------------------------------------------------------
// 4. Fused scores+softmax: attn[bt] = softmax_rows(k[bt] . q[bt]^T / 512).
// Block: 128 score-rows x ALL 512 cols (full row -> single-pass softmax).
// 8 waves (2 wrow x 4 wcol), wave-tile 64x128 -> acc 128 VGPR/lane.
// BK=32, double-buffered staging (kA 2x8K + qB 2x32K = 80K LDS) + 4K reduce.
// Grid 256 blocks (4 mtiles x 64 bt), XCD-swizzled: 8 bt per XCD.
// ---------------------------------------------------------------------------
__global__ __launch_bounds__(512, 2) void scores_softmax(
    const bf16_t* __restrict__ K, const bf16_t* __restrict__ Q,
    bf16_t* __restrict__ P)
{
    int L  = blockIdx.x;                 // 0..255
    int wk = (L & 7) * 32 + (L >> 3);    // bijective XCD swizzle
    int bt = wk >> 2;
    int ti = (wk & 3) << 7;              // score-row tile origin
    const bf16_t* Kb = K + (size_t)bt * 262144;
    const bf16_t* Qb = Q + (size_t)bt * 262144;

    __shared__ __align__(1024) char smem[86016];
    // [0,16384) kA dbuf (2x8K); [16384,81920) qB dbuf (2x32K); then smax, ssum
    float* smax_p = (float*)(smem + 81920);   // [128][4]
    float* ssum_p = (float*)(smem + 83968);   // [128][4]

    const int tid  = threadIdx.x;
    const int l    = tid & 63;
    const int wv   = tid >> 6;           // 0..7
    const int wrow = wv >> 2;            // 0..1 (64 rows each)
    const int wcol = wv & 3;             // 0..3 (128 cols each)
    const int rA   = l & 15;
    const int hb   = l >> 4;             // 0..3

    f32x4 acc[4][8] = {};                // [m 4x16 rows][n 8x16 cols]

    auto stage = [&](int buf, int d0) {
        char* kA = smem + buf * 8192;
        char* qB = smem + 16384 + buf * 32768;
        {   // kA: 128 rows x 64B, 512 lane-loads (1 inst/thread)
            int row = tid >> 2, slot = tid & 3;
            const bf16_t* src = Kb + (size_t)(ti + row) * 512 + d0 + (slot ^ (row & 3)) * 8;
            __builtin_amdgcn_global_load_lds((GAS void*)src, (LAS void*)(kA + tid * 16), 16, 0, 0);
        }
        #pragma unroll
        for (int u = 0; u < 4; ++u) {    // qB: 512 rows x 64B, 2048 lane-loads
            int q2 = u * 512 + tid;
            int row = q2 >> 2, slot = q2 & 3;
            const bf16_t* src = Qb + (size_t)row * 512 + d0 + (slot ^ (row & 3)) * 8;
            __builtin_amdgcn_global_load_lds((GAS void*)src, (LAS void*)(qB + q2 * 16), 16, 0, 0);
        }
    };

    stage(0, 0);
    __syncthreads();
    for (int it = 0; it < 16; ++it) {
        if (it < 15) stage((it + 1) & 1, (it + 1) * 32);
        const char* kA = smem + (it & 1) * 8192;
        const char* qB = smem + 16384 + (it & 1) * 32768;
        bf16x8 a[4], b[8];
        #pragma unroll
        for (int m = 0; m < 4; ++m) {
            int row = wrow * 64 + m * 16 + rA;
            a[m] = *(const bf16x8*)(kA + row * 64 + (hb ^ (row & 3)) * 16);
        }
        #pragma unroll
        for (int n = 0; n < 8; ++n) {
            int row = wcol * 128 + n * 16 + rA;
            b[n] = *(const bf16x8*)(qB + row * 64 + (hb ^ (row & 3)) * 16);
        }
        #pragma unroll
        for (int m = 0; m < 4; ++m)
            #pragma unroll
            for (int n = 0; n < 8; ++n)
                acc[m][n] = __builtin_amdgcn_mfma_f32_16x16x32_bf16(a[m], b[n], acc[m][n], 0, 0, 0);
        __syncthreads();
    }

    // ---- softmax over full 512-col rows ----
    // acc[m][n][r]: row_local = wrow*64+m*16+hb*4+r, col = wcol*128+n*16+rA
    float red[4][4];
    #pragma unroll
    for (int m = 0; m < 4; ++m)
        #pragma unroll
        for (int r = 0; r < 4; ++r) {
            float mx = acc[m][0][r];
            #pragma unroll
            for (int n = 1; n < 8; ++n) mx = fmaxf(mx, acc[m][n][r]);
            #pragma unroll
            for (int o = 1; o < 16; o <<= 1) mx = fmaxf(mx, __shfl_xor(mx, o, 64));
            red[m][r] = mx;   // replicated over the 16-lane group
        }
    if (rA < 4) {
        #pragma unroll
        for (int m = 0; m < 4; ++m)
            smax_p[(wrow * 64 + m * 16 + hb * 4 + rA) * 4 + wcol] = red[m][rA];
    }
    __syncthreads();
    float rstat[4][4];
    #pragma unroll
    for (int m = 0; m < 4; ++m)
        #pragma unroll
        for (int r = 0; r < 4; ++r) {
            f32x4 p4 = *(const f32x4*)(smax_p + (wrow * 64 + m * 16 + hb * 4 + r) * 4);
            rstat[m][r] = fmaxf(fmaxf(p4[0], p4[1]), fmaxf(p4[2], p4[3]));
        }
    const float inv512 = 1.0f / 512.0f;
    #pragma unroll
    for (int m = 0; m < 4; ++m)
        #pragma unroll
        for (int r = 0; r < 4; ++r) {
            float sum = 0.0f;
            #pragma unroll
            for (int n = 0; n < 8; ++n) {
                float e = __expf((acc[m][n][r] - rstat[m][r]) * inv512);
                acc[m][n][r] = e;
                sum += e;
            }
            #pragma unroll
            for (int o = 1; o < 16; o <<= 1) sum += __shfl_xor(sum, o, 64);
            red[m][r] = sum;
        }
    if (rA < 4) {
        #pragma unroll
        for (int m = 0; m < 4; ++m)
            ssum_p[(wrow * 64 + m * 16 + hb * 4 + rA) * 4 + wcol] = red[m][rA];
    }
    __syncthreads();
    #pragma unroll
    for (int m = 0; m < 4; ++m)
        #pragma unroll
        for (int r = 0; r < 4; ++r) {
            f32x4 p4 = *(const f32x4*)(ssum_p + (wrow * 64 + m * 16 + hb * 4 + r) * 4);
            rstat[m][r] = 1.0f / (((p4[0] + p4[1]) + (p4[2] + p4[3])));
        }
    // write attn bf16
    #pragma unroll
    for (int m = 0; m < 4; ++m)
        #pragma unroll
        for (int n = 0; n < 8; ++n) {
            int col = wcol * 128 + n * 16 + rA;
            #pragma unroll
            for (int r = 0; r < 4; ++r) {
                int row = ti + wrow * 64 + m * 16 + hb * 4 + r;
                P[(size_t)bt * 262144 + (size_t)row * 512 + col] =
                    (bf16_t)(acc[m][n][r] * rstat[m][r]);
            }
        }
}

// ---------------------------------------------------------------------------
extern "C" void kernel_launch(void* const* d_in, const int* in_sizes, int n_in,
                              void* d_out, int out_size, void* d_ws, size_t ws_size,
                              hipStream_t stream)
{
    const float* x  = (const float*)d_in[0];
    const float* Wk = (const float*)d_in[1];
    const float* bk = (const float*)d_in[2];
    const float* Wq = (const float*)d_in[3];
    const float* bq = (const float*)d_in[4];
    const float* Wv = (const float*)d_in[5];
    const float* bv = (const float*)d_in[6];
    float* out = (float*)d_out;
    char*  ws  = (char*)d_ws;

    bf16_t* k    = (bf16_t*)(ws + 0);          // 33.55 MB
    bf16_t* q    = (bf16_t*)(ws + 33554432);   // 33.55 MB
    bf16_t* vt   = (bf16_t*)(ws + 67108864);   // 33.55 MB  v^T: [bt][e][j]
    bf16_t* xpe  = (bf16_t*)(ws + 100663296);  // 33.55 MB  (dead after vt gemm)
    bf16_t* attn = xpe;                        // alias over dead xpe
    bf16_t* wkb  = (bf16_t*)(ws + 134217728);
    bf16_t* wqb  = (bf16_t*)(ws + 138412032);
    bf16_t* wvb  = (bf16_t*)(ws + 142606336);

    const long S2 = 262144;  // 512*512 per-(b,t)/per-t stride

    pe_cast_kernel<<<2048, 256, 0, stream>>>(x, xpe);
    cast_w<<<dim3(512, 3), 256, 0, stream>>>(Wk, Wq, Wv, wkb, wqb, wvb, (8 * 512 * 512) / 4);

    dim3 gg(16, 64);
    // k = xpe . Wk^T + bk ; q = xpe . Wq^T + bq ; vT = Wv . xpe^T + bv
    gemm_nt<1, 1><<<gg, 256, 0, stream>>>(xpe, wkb, k, bk, S2, S2, S2, 0, 1, 1.0f);
    gemm_nt<1, 1><<<gg, 256, 0, stream>>>(xpe, wqb, q, bq, S2, S2, S2, 0, 1, 1.0f);
    gemm_nt<2, 1><<<gg, 256, 0, stream>>>(wvb, xpe, vt, bv, S2, S2, S2, 1, 0, 1.0f);
    // attn = softmax(k.q^T/512) fused
    scores_softmax<<<256, 512, 0, stream>>>(k, q, attn);
    // out = attn . v
    gemm_nt<0, 0><<<gg, 256, 0, stream>>>(attn, vt, out, nullptr, S2, S2, S2, 0, 0, 1.0f);
}